// Round 8
// baseline (10815.845 us; speedup 1.0000x reference)
//
#include <hip/hip_runtime.h>

// LSTM_584115552367 — B=65536, T=50, D=17, SLB=30 (runtime).
// Round-8: register-block 2 batch elements per thread. The LDS-pipe model
// now explains r0 (578 us pred / 552 meas) and r7 (760 pred / 959 meas):
// broadcast weight ds_read_b128 at ~12cyc on the shared per-CU LDS pipe is
// the wall. One weight read now feeds 2 b's (8 FMAs vs 4) -> per-CU LDS
// instrs halve: 8 waves x (170 b128 + 68 b32) ~ 19.6 kcyc/step -> ~410 us.
// Block: 4 quarter-waves, 128 b; grid 512 (2 blocks/CU). LDS 54.6 KB.

#define Dn 17
#define Tn 50
#define SROW 35        // sbuf row stride (34 data + 1 pad, odd -> conflict-free)

// g_ws layout (float offsets), all quarter bases 16B-aligned
#define WQ_OFF  0      // [4][34][20] phase-1 weights, j' = gate*5 + ei (padded)
#define CZ_OFF  2720   // [4][17][20] phase-2 folded weights
#define WL_OFF  4080   // [4][17][8]  Wlin quarter (out head), padded 8
#define BS_OFF  4624   // [4][20]     phase-1 bias
#define BC_OFF  4704   // [4][20]     phase-2 folded bias
#define BL_OFF  4784   // [4][8]      b_lin quarter
#define WS_FLOATS 4816

__device__ __align__(16) float g_ws[WS_FLOATS];

__device__ __forceinline__ float sigm_(float v) {
    float e = __expf(-v);
    return __builtin_amdgcn_rcpf(1.0f + e);
}
__device__ __forceinline__ float tanh_(float v) {
    float e = __expf(2.0f * v);
    return 1.0f - 2.0f * __builtin_amdgcn_rcpf(e + 1.0f);
}
__device__ __forceinline__ float getc(const float4 v, int c) {
    return c == 0 ? v.x : c == 1 ? v.y : c == 2 ? v.z : v.w;
}
__device__ __forceinline__ void fma4(float4& a, float b, const float4 w) {
    a.x = __builtin_fmaf(b, w.x, a.x);
    a.y = __builtin_fmaf(b, w.y, a.y);
    a.z = __builtin_fmaf(b, w.z, a.z);
    a.w = __builtin_fmaf(b, w.w, a.w);
}

__global__ void lstm_setup(const float* __restrict__ W_ih, const float* __restrict__ W_hh,
                           const float* __restrict__ b_ih, const float* __restrict__ b_hh,
                           const float* __restrict__ W_lin, const float* __restrict__ b_lin,
                           const float* __restrict__ m_ih, const float* __restrict__ m_hh)
{
    __shared__ float A[68 * Dn];
    __shared__ float Bm[68 * Dn];
    const int tid = threadIdx.x;
    for (int i = tid; i < 68 * Dn; i += 256) {
        A[i]  = W_ih[i] * m_ih[i];
        Bm[i] = W_hh[i] * m_hh[i];
    }
    __syncthreads();
    // WQ[q][k][j']  (j' = g*5+ei; e = e0(q)+ei; j = g*17+e)
    for (int idx = tid; idx < 4 * 34 * 20; idx += 256) {
        int q = idx / 680, r = idx % 680, k = r / 20, jp = r % 20, g = jp / 5, ei = jp % 5;
        int nE = q ? 4 : 5, e0 = q ? (1 + 4 * q) : 0;
        float v = 0.0f;
        if (ei < nE) {
            int j = g * 17 + e0 + ei;
            v = (k < Dn) ? A[j * Dn + k] : Bm[j * Dn + (k - Dn)];
        }
        g_ws[WQ_OFF + idx] = v;
    }
    // CZ[q][k][j'] = B[j][k] + sum_m A[j][m] * W_lin[m][k]
    for (int idx = tid; idx < 4 * 17 * 20; idx += 256) {
        int q = idx / 340, r = idx % 340, k = r / 20, jp = r % 20, g = jp / 5, ei = jp % 5;
        int nE = q ? 4 : 5, e0 = q ? (1 + 4 * q) : 0;
        float v = 0.0f;
        if (ei < nE) {
            int j = g * 17 + e0 + ei;
            v = Bm[j * Dn + k];
            for (int m = 0; m < Dn; ++m) v = __builtin_fmaf(A[j * Dn + m], W_lin[m * Dn + k], v);
        }
        g_ws[CZ_OFF + idx] = v;
    }
    // WL[q][k][ei] = W_lin[e][k]
    for (int idx = tid; idx < 4 * 17 * 8; idx += 256) {
        int q = idx / 136, r = idx % 136, k = r / 8, ei = r % 8;
        int nE = q ? 4 : 5, e0 = q ? (1 + 4 * q) : 0;
        g_ws[WL_OFF + idx] = (ei < nE) ? W_lin[(e0 + ei) * Dn + k] : 0.0f;
    }
    // BS / BC
    for (int idx = tid; idx < 4 * 20; idx += 256) {
        int q = idx / 20, jp = idx % 20, g = jp / 5, ei = jp % 5;
        int nE = q ? 4 : 5, e0 = q ? (1 + 4 * q) : 0;
        float vs = 0.0f, vc = 0.0f;
        if (ei < nE) {
            int j = g * 17 + e0 + ei;
            vs = b_ih[j] + b_hh[j];
            vc = vs;
            for (int m = 0; m < Dn; ++m) vc = __builtin_fmaf(A[j * Dn + m], b_lin[m], vc);
        }
        g_ws[BS_OFF + idx] = vs;
        g_ws[BC_OFF + idx] = vc;
    }
    // BL
    for (int idx = tid; idx < 4 * 8; idx += 256) {
        int q = idx / 8, ei = idx % 8;
        int nE = q ? 4 : 5, e0 = q ? (1 + 4 * q) : 0;
        g_ws[BL_OFF + idx] = (ei < nE) ? b_lin[e0 + ei] : 0.0f;
    }
}

__global__ __launch_bounds__(256, 2)
void lstm_main(const float* __restrict__ x,
               const int* __restrict__ slb_p, float* __restrict__ out)
{
    __shared__ __align__(16) float sW[WS_FLOATS];   // prepared weights (19.3 KB)
    __shared__ float sbuf[128 * SROW];              // x / out staging, 2-step groups (17.9 KB)
    __shared__ float hbuf[2][128 * Dn];             // double-buffered h exchange (17.4 KB)

    const int tid = threadIdx.x;
    const int q   = tid >> 6;            // wave index == quarter role
    const int l   = tid & 63;            // first batch element; second is l+64
    const int b0  = blockIdx.x * 128;
    const int nE  = q ? 4 : 5;
    const int e0  = q ? (1 + 4 * q) : 0; // e-ranges: [0..4],[5..8],[9..12],[13..16]

    for (int i = tid; i < WS_FLOATS; i += 256) sW[i] = g_ws[i];

    const float4* wq4 = (const float4*)(sW + WQ_OFF + q * 680);
    const float4* cz4 = (const float4*)(sW + CZ_OFF + q * 340);
    const float4* wl4 = (const float4*)(sW + WL_OFF + q * 136);
    const float4* bs4 = (const float4*)(sW + BS_OFF + q * 20);
    const float4* bc4 = (const float4*)(sW + BC_OFF + q * 20);
    const float4* bl4 = (const float4*)(sW + BL_OFF + q * 8);

    for (int i = tid; i < 128 * Dn; i += 256) hbuf[0][i] = 0.0f;
    __syncthreads();

    const int slb  = slb_p[0];
    const int nout = Tn - slb;

    float c[2][5];
    #pragma unroll
    for (int bi = 0; bi < 2; ++bi)
        #pragma unroll
        for (int e = 0; e < 5; ++e) c[bi][e] = 0.0f;

    int p = 0;

    // ---- phase 1: teacher-forced, 2-step groups ----
    for (int t0 = 0; t0 < slb; t0 += 2) {
        // bulk-load 2 timesteps of x for all 128 b, f-ordered contiguous
        {
            const int base = t0 * Dn;
            #pragma unroll
            for (int i = 0; i < 17; ++i) {
                int f  = tid + 256 * i;          // 0..4351 = 128*34 exact
                int bb = f / 34;
                int rr = f - 34 * bb;
                int ro = base + rr;
                if (ro > Tn * Dn - 1) ro = Tn * Dn - 1;   // clamp (junk never consumed)
                sbuf[bb * SROW + rr] = x[(long)(b0 + bb) * (Tn * Dn) + ro];
            }
        }
        __syncthreads();
        const int gs = (slb - t0 < 2) ? (slb - t0) : 2;
        for (int ts = 0; ts < gs; ++ts) {
            const float* xr0 = &sbuf[l * SROW + ts * Dn];
            const float* xr1 = &sbuf[(l + 64) * SROW + ts * Dn];
            const float* hr0 = &hbuf[p][l * Dn];
            const float* hr1 = &hbuf[p][(l + 64) * Dn];
            float4 a0[5], a1[5];
            #pragma unroll
            for (int j = 0; j < 5; ++j) { a0[j] = bs4[j]; a1[j] = a0[j]; }
            #pragma unroll
            for (int k = 0; k < Dn; ++k) {       // x part: 1 weight read feeds 2 b
                float z0 = xr0[k], z1 = xr1[k];
                const float4* w4 = wq4 + k * 5;
                #pragma unroll
                for (int j = 0; j < 5; ++j) { float4 w = w4[j]; fma4(a0[j], z0, w); fma4(a1[j], z1, w); }
            }
            #pragma unroll
            for (int k = 0; k < Dn; ++k) {       // h part
                float z0 = hr0[k], z1 = hr1[k];
                const float4* w4 = wq4 + (Dn + k) * 5;
                #pragma unroll
                for (int j = 0; j < 5; ++j) { float4 w = w4[j]; fma4(a0[j], z0, w); fma4(a1[j], z1, w); }
            }
            float* hw0 = &hbuf[p ^ 1][l * Dn + e0];
            float* hw1 = &hbuf[p ^ 1][(l + 64) * Dn + e0];
            #pragma unroll
            for (int ei = 0; ei < 5; ++ei) {     // indices fold to consts after unroll
                float gi = getc(a0[(0 + ei) >> 2], (0 + ei) & 3);
                float gf = getc(a0[(5 + ei) >> 2], (5 + ei) & 3);
                float gg = getc(a0[(10 + ei) >> 2], (10 + ei) & 3);
                float go = getc(a0[(15 + ei) >> 2], (15 + ei) & 3);
                float cv = __builtin_fmaf(sigm_(gf), c[0][ei], sigm_(gi) * tanh_(gg));
                c[0][ei] = cv;
                float hn = sigm_(go) * tanh_(cv);
                if (ei < nE) hw0[ei] = hn;
            }
            #pragma unroll
            for (int ei = 0; ei < 5; ++ei) {
                float gi = getc(a1[(0 + ei) >> 2], (0 + ei) & 3);
                float gf = getc(a1[(5 + ei) >> 2], (5 + ei) & 3);
                float gg = getc(a1[(10 + ei) >> 2], (10 + ei) & 3);
                float go = getc(a1[(15 + ei) >> 2], (15 + ei) & 3);
                float cv = __builtin_fmaf(sigm_(gf), c[1][ei], sigm_(gi) * tanh_(gg));
                c[1][ei] = cv;
                float hn = sigm_(go) * tanh_(cv);
                if (ei < nE) hw1[ei] = hn;
            }
            __syncthreads();
            p ^= 1;
        }
    }

    // ---- phase 2: free-running, 2-step groups with staged coalesced output ----
    for (int tp0 = 0; tp0 < nout; tp0 += 2) {
        const int gs = (nout - tp0 < 2) ? (nout - tp0) : 2;
        for (int ts = 0; ts < gs; ++ts) {
            const float* hr0 = &hbuf[p][l * Dn];
            const float* hr1 = &hbuf[p][(l + 64) * Dn];
            float4 a0[5], a1[5];
            #pragma unroll
            for (int j = 0; j < 5; ++j) { a0[j] = bc4[j]; a1[j] = a0[j]; }
            #pragma unroll
            for (int k = 0; k < Dn; ++k) {
                float z0 = hr0[k], z1 = hr1[k];
                const float4* w4 = cz4 + k * 5;
                #pragma unroll
                for (int j = 0; j < 5; ++j) { float4 w = w4[j]; fma4(a0[j], z0, w); fma4(a1[j], z1, w); }
            }
            float* hw0 = &hbuf[p ^ 1][l * Dn + e0];
            float* hw1 = &hbuf[p ^ 1][(l + 64) * Dn + e0];
            #pragma unroll
            for (int ei = 0; ei < 5; ++ei) {
                float gi = getc(a0[(0 + ei) >> 2], (0 + ei) & 3);
                float gf = getc(a0[(5 + ei) >> 2], (5 + ei) & 3);
                float gg = getc(a0[(10 + ei) >> 2], (10 + ei) & 3);
                float go = getc(a0[(15 + ei) >> 2], (15 + ei) & 3);
                float cv = __builtin_fmaf(sigm_(gf), c[0][ei], sigm_(gi) * tanh_(gg));
                c[0][ei] = cv;
                float hn = sigm_(go) * tanh_(cv);
                if (ei < nE) hw0[ei] = hn;
            }
            #pragma unroll
            for (int ei = 0; ei < 5; ++ei) {
                float gi = getc(a1[(0 + ei) >> 2], (0 + ei) & 3);
                float gf = getc(a1[(5 + ei) >> 2], (5 + ei) & 3);
                float gg = getc(a1[(10 + ei) >> 2], (10 + ei) & 3);
                float go = getc(a1[(15 + ei) >> 2], (15 + ei) & 3);
                float cv = __builtin_fmaf(sigm_(gf), c[1][ei], sigm_(gi) * tanh_(gg));
                c[1][ei] = cv;
                float hn = sigm_(go) * tanh_(cv);
                if (ei < nE) hw1[ei] = hn;
            }
            __syncthreads();
            // head on the freshly-exchanged full h; stash slices into sbuf
            const float* h20 = &hbuf[p ^ 1][l * Dn];
            const float* h21 = &hbuf[p ^ 1][(l + 64) * Dn];
            float4 o0[2] = { bl4[0], bl4[1] };
            float4 o1[2] = { bl4[0], bl4[1] };
            #pragma unroll
            for (int k = 0; k < Dn; ++k) {
                float hk0 = h20[k], hk1 = h21[k];
                float4 w0 = wl4[k * 2 + 0], w1 = wl4[k * 2 + 1];
                fma4(o0[0], hk0, w0); fma4(o0[1], hk0, w1);
                fma4(o1[0], hk1, w0); fma4(o1[1], hk1, w1);
            }
            float* ow0 = &sbuf[l * SROW + ts * Dn + e0];
            float* ow1 = &sbuf[(l + 64) * SROW + ts * Dn + e0];
            #pragma unroll
            for (int ei = 0; ei < 5; ++ei)
                if (ei < nE) { ow0[ei] = getc(o0[ei >> 2], ei & 3); ow1[ei] = getc(o1[ei >> 2], ei & 3); }
            p ^= 1;
        }
        __syncthreads();   // sbuf tile complete across all waves
        // bulk store: per b, gs*17 contiguous floats of the out row
        if (gs == 2) {
            #pragma unroll
            for (int i = 0; i < 17; ++i) {
                int f  = tid + 256 * i;          // 0..4351 = 128*34 exact
                int bb = f / 34;
                int rr = f - 34 * bb;
                out[(long)(b0 + bb) * (nout * Dn) + tp0 * Dn + rr] = sbuf[bb * SROW + rr];
            }
        } else {
            for (int f = tid; f < 128 * Dn; f += 256) {
                int bb = f / Dn;
                int rr = f - Dn * bb;
                out[(long)(b0 + bb) * (nout * Dn) + tp0 * Dn + rr] = sbuf[bb * SROW + rr];
            }
        }
        // next group's sbuf writes happen only after its own compute barriers -> safe
    }
}

extern "C" void kernel_launch(void* const* d_in, const int* in_sizes, int n_in,
                              void* d_out, int out_size, void* d_ws, size_t ws_size,
                              hipStream_t stream) {
    (void)in_sizes; (void)n_in; (void)ws_size; (void)out_size; (void)d_ws;
    const float* x     = (const float*)d_in[0];
    const float* W_ih  = (const float*)d_in[1];
    const float* W_hh  = (const float*)d_in[2];
    const float* b_ih  = (const float*)d_in[3];
    const float* b_hh  = (const float*)d_in[4];
    const float* W_lin = (const float*)d_in[5];
    const float* b_lin = (const float*)d_in[6];
    const float* m_ih  = (const float*)d_in[7];
    const float* m_hh  = (const float*)d_in[8];
    const int*   slb   = (const int*)d_in[9];
    float* out = (float*)d_out;

    lstm_setup<<<dim3(1), dim3(256), 0, stream>>>(
        W_ih, W_hh, b_ih, b_hh, W_lin, b_lin, m_ih, m_hh);
    lstm_main<<<dim3(512), dim3(256), 0, stream>>>(x, slb, out);
}

// Round 9
// 1034.089 us; speedup vs baseline: 10.4593x; 10.4593x over previous
//
#include <hip/hip_runtime.h>

// LSTM_584115552367 — B=65536, T=50, D=17, SLB=30 (runtime).
// Round-9: r0's proven-clean shape (full-gate thread, static arrays, getc
// extraction — zero phantom traffic) + ONE change: 2 batch elements per
// thread, 128-thread blocks, grid 256 (1 block/CU). Calibrated LDS model
// (broadcast b128 ~12cyc; r0 pred 496/meas 552; r7 pred/meas match): the
// wall is weight-b128 per CU = sweeps x 578. This halves sweeps 4->2 waves
// while doubling FMA per read. h/c now fully register-resident (thread-
// private). Predicted ~280-380 us, hbm back to ~0.2 GB.

#define Dn 17
#define Gn 68
#define Tn 50
#define WS 68          // gate-row width (17 float4, 272 B rows, 16B-aligned)
#define ZS 35          // zbuf row: [x_even 17 | x_odd 17 | pad] (h in regs now)
#define NT 128         // threads per block
#define NB 256         // batch elements per block (2 per thread)

__device__ __forceinline__ float sigm_(float v) {
    float e = __expf(-v);
    return __builtin_amdgcn_rcpf(1.0f + e);
}
__device__ __forceinline__ float tanh_(float v) {
    float e = __expf(2.0f * v);
    return 1.0f - 2.0f * __builtin_amdgcn_rcpf(e + 1.0f);
}
__device__ __forceinline__ float getc(const float4 v, int c) {
    return c == 0 ? v.x : c == 1 ? v.y : c == 2 ? v.z : v.w;
}
__device__ __forceinline__ void fma4(float4& a, float b, const float4 w) {
    a.x = __builtin_fmaf(b, w.x, a.x);
    a.y = __builtin_fmaf(b, w.y, a.y);
    a.z = __builtin_fmaf(b, w.z, a.z);
    a.w = __builtin_fmaf(b, w.w, a.w);
}

__global__ __launch_bounds__(NT, 1)
void lstm_fused(const float* __restrict__ x,
                const float* __restrict__ W_ih, const float* __restrict__ W_hh,
                const float* __restrict__ b_ih, const float* __restrict__ b_hh,
                const float* __restrict__ W_lin, const float* __restrict__ b_lin,
                const float* __restrict__ m_ih, const float* __restrict__ m_hh,
                const int* __restrict__ slb_p, float* __restrict__ out)
{
    __shared__ __align__(16) float sWzT[2 * Dn * WS];  // rows k<17: A^T(x); 17..33: B^T(h)
    __shared__ __align__(16) float sCzT[Dn * WS];      // free-running fold, transposed
    __shared__ __align__(16) float sWlT[Dn * 20];      // Wlin^T rows padded to 20
    __shared__ __align__(16) float sBs[WS];            // b_ih + b_hh
    __shared__ __align__(16) float sBc[WS];            // folded phase-2 bias
    __shared__ __align__(16) float sBl[20];            // b_lin (padded)
    __shared__ float tmpA[Gn * Dn];
    __shared__ float tmpB[Gn * Dn];
    __shared__ float zbuf[NB * ZS];                    // x staging only
    __shared__ float obuf[NB * Dn];

    const int tid = threadIdx.x;
    const int b0  = blockIdx.x * NB;

    // ---- setup: masked weights, transposes, free-running fold ----
    for (int i = tid; i < Gn * Dn; i += NT) {
        tmpA[i] = W_ih[i] * m_ih[i];
        tmpB[i] = W_hh[i] * m_hh[i];
    }
    for (int i = tid; i < Dn * 20; i += NT) {
        int k = i / 20, m = i - 20 * k;
        sWlT[i] = (m < Dn) ? W_lin[m * Dn + k] : 0.0f;
    }
    if (tid < WS) sBs[tid] = b_ih[tid] + b_hh[tid];
    if (tid < 20) sBl[tid] = (tid < Dn) ? b_lin[tid] : 0.0f;
    __syncthreads();
    for (int i = tid; i < 2 * Dn * WS; i += NT) {
        int k = i / WS, j = i - WS * k;
        sWzT[i] = (k < Dn) ? tmpA[j * Dn + k] : tmpB[j * Dn + (k - Dn)];
    }
    for (int i = tid; i < Dn * WS; i += NT) {
        int k = i / WS, j = i - WS * k;
        float v = tmpB[j * Dn + k];
        #pragma unroll
        for (int m = 0; m < Dn; ++m) v = __builtin_fmaf(tmpA[j * Dn + m], sWlT[k * 20 + m], v);
        sCzT[i] = v;
    }
    if (tid < Gn) {
        float v = sBs[tid];
        #pragma unroll
        for (int m = 0; m < Dn; ++m) v = __builtin_fmaf(tmpA[tid * Dn + m], sBl[m], v);
        sBc[tid] = v;
    }

    // ---- stage x(t=0) into parity-0 slots (f-pattern, coalesced) ----
    #pragma unroll
    for (int i = 0; i < 34; ++i) {
        int f  = tid + NT * i;               // 0..4351 = 256 rows x 17
        int br = f / Dn, d = f - Dn * br;
        zbuf[br * ZS + d] = x[(b0 + br) * (Tn * Dn) + d];
    }
    __syncthreads();

    const int slb = slb_p[0];
    float c0_[Dn], c1_[Dn], h0_[Dn], h1_[Dn];
    #pragma unroll
    for (int e = 0; e < Dn; ++e) { c0_[e] = 0.0f; c1_[e] = 0.0f; h0_[e] = 0.0f; h1_[e] = 0.0f; }

    const float* zr0 = &zbuf[tid * ZS];
    const float* zr1 = &zbuf[(tid + NT) * ZS];
    const float4* bs4 = (const float4*)sBs;

    // ---- phase 1: teacher-forced ----
    for (int t = 0; t < slb; ++t) {
        const bool pre = (t + 1 < slb);
        float gx[34];
        if (pre) {
            #pragma unroll
            for (int i = 0; i < 34; ++i) {
                int f  = tid + NT * i;
                int br = f / Dn, d = f - Dn * br;
                gx[i] = x[(b0 + br) * (Tn * Dn) + (t + 1) * Dn + d];
            }
        }
        float4 a0[Dn], a1[Dn];
        #pragma unroll
        for (int j = 0; j < Dn; ++j) { a0[j] = bs4[j]; a1[j] = bs4[j]; }
        const int xo = (t & 1) * Dn;
        #pragma unroll 2
        for (int k = 0; k < Dn; ++k) {           // x part: 1 weight b128 feeds 2 b
            float z0 = zr0[xo + k], z1 = zr1[xo + k];
            const float4* w4 = (const float4*)&sWzT[k * WS];
            #pragma unroll
            for (int j = 0; j < Dn; ++j) { float4 w = w4[j]; fma4(a0[j], z0, w); fma4(a1[j], z1, w); }
        }
        #pragma unroll 2
        for (int k = 0; k < Dn; ++k) {           // h part: h register-resident
            float z0 = h0_[k], z1 = h1_[k];
            const float4* w4 = (const float4*)&sWzT[(Dn + k) * WS];
            #pragma unroll
            for (int j = 0; j < Dn; ++j) { float4 w = w4[j]; fma4(a0[j], z0, w); fma4(a1[j], z1, w); }
        }
        #pragma unroll
        for (int e = 0; e < Dn; ++e) {
            float gi = getc(a0[e >> 2], e & 3);
            float gf = getc(a0[(Dn + e) >> 2], (Dn + e) & 3);
            float gg = getc(a0[(2 * Dn + e) >> 2], (2 * Dn + e) & 3);
            float go = getc(a0[(3 * Dn + e) >> 2], (3 * Dn + e) & 3);
            float cv = __builtin_fmaf(sigm_(gf), c0_[e], sigm_(gi) * tanh_(gg));
            c0_[e] = cv;
            h0_[e] = sigm_(go) * tanh_(cv);
        }
        #pragma unroll
        for (int e = 0; e < Dn; ++e) {
            float gi = getc(a1[e >> 2], e & 3);
            float gf = getc(a1[(Dn + e) >> 2], (Dn + e) & 3);
            float gg = getc(a1[(2 * Dn + e) >> 2], (2 * Dn + e) & 3);
            float go = getc(a1[(3 * Dn + e) >> 2], (3 * Dn + e) & 3);
            float cv = __builtin_fmaf(sigm_(gf), c1_[e], sigm_(gi) * tanh_(gg));
            c1_[e] = cv;
            h1_[e] = sigm_(go) * tanh_(cv);
        }
        if (pre) {
            const int xo2 = ((t + 1) & 1) * Dn;
            #pragma unroll
            for (int i = 0; i < 34; ++i) {
                int f  = tid + NT * i;
                int br = f / Dn, d = f - Dn * br;
                zbuf[br * ZS + xo2 + d] = gx[i];
            }
        }
        __syncthreads();
    }

    // ---- phase 2: free-running (h/c in regs; LDS only for out transpose) ----
    const int nout = Tn - slb;
    const int ostr = nout * Dn;
    const float4* bc4 = (const float4*)sBc;
    const float4* bl4 = (const float4*)sBl;

    for (int tp = 0; tp < nout; ++tp) {
        float4 a0[Dn], a1[Dn];
        #pragma unroll
        for (int j = 0; j < Dn; ++j) { a0[j] = bc4[j]; a1[j] = bc4[j]; }
        #pragma unroll 2
        for (int k = 0; k < Dn; ++k) {
            float z0 = h0_[k], z1 = h1_[k];
            const float4* w4 = (const float4*)&sCzT[k * WS];
            #pragma unroll
            for (int j = 0; j < Dn; ++j) { float4 w = w4[j]; fma4(a0[j], z0, w); fma4(a1[j], z1, w); }
        }
        #pragma unroll
        for (int e = 0; e < Dn; ++e) {
            float gi = getc(a0[e >> 2], e & 3);
            float gf = getc(a0[(Dn + e) >> 2], (Dn + e) & 3);
            float gg = getc(a0[(2 * Dn + e) >> 2], (2 * Dn + e) & 3);
            float go = getc(a0[(3 * Dn + e) >> 2], (3 * Dn + e) & 3);
            float cv = __builtin_fmaf(sigm_(gf), c0_[e], sigm_(gi) * tanh_(gg));
            c0_[e] = cv;
            h0_[e] = sigm_(go) * tanh_(cv);
        }
        #pragma unroll
        for (int e = 0; e < Dn; ++e) {
            float gi = getc(a1[e >> 2], e & 3);
            float gf = getc(a1[(Dn + e) >> 2], (Dn + e) & 3);
            float gg = getc(a1[(2 * Dn + e) >> 2], (2 * Dn + e) & 3);
            float go = getc(a1[(3 * Dn + e) >> 2], (3 * Dn + e) & 3);
            float cv = __builtin_fmaf(sigm_(gf), c1_[e], sigm_(gi) * tanh_(gg));
            c1_[e] = cv;
            h1_[e] = sigm_(go) * tanh_(cv);
        }
        // linear head from registers (one weight read feeds both b)
        float4 o0[5], o1[5];
        #pragma unroll
        for (int j = 0; j < 5; ++j) { o0[j] = bl4[j]; o1[j] = bl4[j]; }
        #pragma unroll
        for (int k = 0; k < Dn; ++k) {
            const float4* w4 = (const float4*)&sWlT[k * 20];
            #pragma unroll
            for (int j = 0; j < 5; ++j) { float4 w = w4[j]; fma4(o0[j], h0_[k], w); fma4(o1[j], h1_[k], w); }
        }
        #pragma unroll
        for (int m = 0; m < Dn; ++m) {
            obuf[tid * Dn + m]        = getc(o0[m >> 2], m & 3);
            obuf[(tid + NT) * Dn + m] = getc(o1[m >> 2], m & 3);
        }
        __syncthreads();
        #pragma unroll
        for (int i = 0; i < 34; ++i) {
            int f  = tid + NT * i;               // obuf row-major: obuf[f] = row f/17, elem f%17
            int br = f / Dn, d = f - Dn * br;
            out[(b0 + br) * ostr + tp * Dn + d] = obuf[f];
        }
        __syncthreads();
    }
}

extern "C" void kernel_launch(void* const* d_in, const int* in_sizes, int n_in,
                              void* d_out, int out_size, void* d_ws, size_t ws_size,
                              hipStream_t stream) {
    (void)in_sizes; (void)n_in; (void)d_ws; (void)ws_size; (void)out_size;
    const float* x     = (const float*)d_in[0];
    const float* W_ih  = (const float*)d_in[1];
    const float* W_hh  = (const float*)d_in[2];
    const float* b_ih  = (const float*)d_in[3];
    const float* b_hh  = (const float*)d_in[4];
    const float* W_lin = (const float*)d_in[5];
    const float* b_lin = (const float*)d_in[6];
    const float* m_ih  = (const float*)d_in[7];
    const float* m_hh  = (const float*)d_in[8];
    const int*   slb   = (const int*)d_in[9];
    float* out = (float*)d_out;

    lstm_fused<<<dim3(256), dim3(NT), 0, stream>>>(
        x, W_ih, W_hh, b_ih, b_hh, W_lin, b_lin, m_ih, m_hh, slb, out);
}

// Round 10
// 823.410 us; speedup vs baseline: 13.1354x; 1.2559x over previous
//
#include <hip/hip_runtime.h>

// LSTM_584115552367 — B=65536, T=50, D=17, SLB=30 (runtime).
// Round-10: quarter-split x nb=4 (4 threads/b gate-split, 4 b/thread),
// 256-thread blocks, grid 256 -> 4 waves/CU (r0's proven LDS-feed level)
// with per-CU LDS work cut 2.7x vs r0: 4 waves x (170 wgt + 34 z + 5 hw)
// b128 ~ 10 kcyc/step vs r0's 27.7. State transposed [elem][batch] so one
// aligned float4 serves a lane's 4 b's. Spill-curse mitigation: compile at
// launch_bounds(256,1) (the caps in r4-r8 correlate with every spill);
// named static arrays a0..a3/c0..c3 (r9-proven clean idiom); no ptr casts
// of accumulators; getc const-index extraction.

#define Dn 17
#define Tn 50
#define RS 260           // row stride for transposed tiles (mult of 4 for float4)
#define XTS (Dn * RS)    // one t-slice / h-buffer size

// g_ws layout (float offsets), quarter bases 16B-aligned (r8 setup, proven)
#define WQ_OFF  0      // [4][34][20] phase-1 weights, j' = gate*5 + ei (padded)
#define CZ_OFF  2720   // [4][17][20] phase-2 folded weights
#define WL_OFF  4080   // [4][17][8]  Wlin quarter (out head), padded 8
#define BS_OFF  4624   // [4][20]     phase-1 bias
#define BC_OFF  4704   // [4][20]     phase-2 folded bias
#define BL_OFF  4784   // [4][8]      b_lin quarter
#define WS_FLOATS 4816

__device__ __align__(16) float g_ws[WS_FLOATS];

__device__ __forceinline__ float sigm_(float v) {
    float e = __expf(-v);
    return __builtin_amdgcn_rcpf(1.0f + e);
}
__device__ __forceinline__ float tanh_(float v) {
    float e = __expf(2.0f * v);
    return 1.0f - 2.0f * __builtin_amdgcn_rcpf(e + 1.0f);
}
__device__ __forceinline__ float getc(const float4 v, int c) {
    return c == 0 ? v.x : c == 1 ? v.y : c == 2 ? v.z : v.w;
}
__device__ __forceinline__ void fma4(float4& a, float b, const float4 w) {
    a.x = __builtin_fmaf(b, w.x, a.x);
    a.y = __builtin_fmaf(b, w.y, a.y);
    a.z = __builtin_fmaf(b, w.z, a.z);
    a.w = __builtin_fmaf(b, w.w, a.w);
}

__global__ void lstm_setup(const float* __restrict__ W_ih, const float* __restrict__ W_hh,
                           const float* __restrict__ b_ih, const float* __restrict__ b_hh,
                           const float* __restrict__ W_lin, const float* __restrict__ b_lin,
                           const float* __restrict__ m_ih, const float* __restrict__ m_hh)
{
    __shared__ float A[68 * Dn];
    __shared__ float Bm[68 * Dn];
    const int tid = threadIdx.x;
    for (int i = tid; i < 68 * Dn; i += 256) {
        A[i]  = W_ih[i] * m_ih[i];
        Bm[i] = W_hh[i] * m_hh[i];
    }
    __syncthreads();
    for (int idx = tid; idx < 4 * 34 * 20; idx += 256) {
        int q = idx / 680, r = idx % 680, k = r / 20, jp = r % 20, g = jp / 5, ei = jp % 5;
        int nE = q ? 4 : 5, e0 = q ? (1 + 4 * q) : 0;
        float v = 0.0f;
        if (ei < nE) {
            int j = g * 17 + e0 + ei;
            v = (k < Dn) ? A[j * Dn + k] : Bm[j * Dn + (k - Dn)];
        }
        g_ws[WQ_OFF + idx] = v;
    }
    for (int idx = tid; idx < 4 * 17 * 20; idx += 256) {
        int q = idx / 340, r = idx % 340, k = r / 20, jp = r % 20, g = jp / 5, ei = jp % 5;
        int nE = q ? 4 : 5, e0 = q ? (1 + 4 * q) : 0;
        float v = 0.0f;
        if (ei < nE) {
            int j = g * 17 + e0 + ei;
            v = Bm[j * Dn + k];
            for (int m = 0; m < Dn; ++m) v = __builtin_fmaf(A[j * Dn + m], W_lin[m * Dn + k], v);
        }
        g_ws[CZ_OFF + idx] = v;
    }
    for (int idx = tid; idx < 4 * 17 * 8; idx += 256) {
        int q = idx / 136, r = idx % 136, k = r / 8, ei = r % 8;
        int nE = q ? 4 : 5, e0 = q ? (1 + 4 * q) : 0;
        g_ws[WL_OFF + idx] = (ei < nE) ? W_lin[(e0 + ei) * Dn + k] : 0.0f;
    }
    for (int idx = tid; idx < 4 * 20; idx += 256) {
        int q = idx / 20, jp = idx % 20, g = jp / 5, ei = jp % 5;
        int nE = q ? 4 : 5, e0 = q ? (1 + 4 * q) : 0;
        float vs = 0.0f, vc = 0.0f;
        if (ei < nE) {
            int j = g * 17 + e0 + ei;
            vs = b_ih[j] + b_hh[j];
            vc = vs;
            for (int m = 0; m < Dn; ++m) vc = __builtin_fmaf(A[j * Dn + m], b_lin[m], vc);
        }
        g_ws[BS_OFF + idx] = vs;
        g_ws[BC_OFF + idx] = vc;
    }
    for (int idx = tid; idx < 4 * 8; idx += 256) {
        int q = idx / 8, ei = idx % 8;
        int nE = q ? 4 : 5, e0 = q ? (1 + 4 * q) : 0;
        g_ws[BL_OFF + idx] = (ei < nE) ? b_lin[e0 + ei] : 0.0f;
    }
}

// gate nonlinearity for one b (accumulator array A, cell ref CC, h output OUTC)
#define GATE4(A, CC, OUTC) { \
    float gi = getc(A[(ei) >> 2], (ei) & 3); \
    float gf = getc(A[(5 + ei) >> 2], (5 + ei) & 3); \
    float gg = getc(A[(10 + ei) >> 2], (10 + ei) & 3); \
    float go = getc(A[(15 + ei) >> 2], (15 + ei) & 3); \
    float cv = __builtin_fmaf(sigm_(gf), CC, sigm_(gi) * tanh_(gg)); \
    CC = cv; OUTC = sigm_(go) * tanh_(cv); }

__global__ __launch_bounds__(256, 1)
void lstm_main(const float* __restrict__ x,
               const int* __restrict__ slb_p, float* __restrict__ out)
{
    __shared__ __align__(16) float sW[WS_FLOATS];  // prepared weights (18.8 KB)
    __shared__ __align__(16) float xt[2 * XTS];    // phase1: x 2-step tile [ts][d][b]; phase2: out tile
    __shared__ __align__(16) float hb[2][XTS];     // double-buffered h, transposed [e][b]

    const int tid = threadIdx.x;
    const int q   = tid >> 6;            // wave index == quarter role
    const int l   = tid & 63;
    const int bq  = 4 * l;               // this thread's b-quad offset within 256
    const int b0  = blockIdx.x * 256;
    const int nE  = q ? 4 : 5;
    const int e0  = q ? (1 + 4 * q) : 0;

    for (int i = tid; i < WS_FLOATS; i += 256) sW[i] = g_ws[i];
    for (int i = tid; i < XTS; i += 256) hb[0][i] = 0.0f;

    const float4* wq4 = (const float4*)(sW + WQ_OFF + q * 680);
    const float4* cz4 = (const float4*)(sW + CZ_OFF + q * 340);
    const float4* wl4 = (const float4*)(sW + WL_OFF + q * 136);
    const float4* bs4 = (const float4*)(sW + BS_OFF + q * 20);
    const float4* bc4 = (const float4*)(sW + BC_OFF + q * 20);
    const float4* bl4 = (const float4*)(sW + BL_OFF + q * 8);
    __syncthreads();

    const int slb  = slb_p[0];
    const int nout = Tn - slb;

    float c0[5], c1[5], c2[5], c3[5];
    #pragma unroll
    for (int e = 0; e < 5; ++e) { c0[e] = 0.0f; c1[e] = 0.0f; c2[e] = 0.0f; c3[e] = 0.0f; }

    int p = 0;

    // ---- phase 1: teacher-forced, 2-step x tiles, transposed staging ----
    for (int t0 = 0; t0 < slb; t0 += 2) {
        #pragma unroll
        for (int i = 0; i < 34; ++i) {
            int f  = tid + 256 * i;          // 0..8703 = 256 b x 34
            int bb = f / 34, rr = f - 34 * bb;
            int ts = rr / Dn, d = rr - Dn * ts;
            int tr = t0 + ts; if (tr > Tn - 1) tr = Tn - 1;
            xt[ts * XTS + d * RS + bb] = x[(long)(b0 + bb) * (Tn * Dn) + tr * Dn + d];
        }
        __syncthreads();
        int gs = slb - t0; if (gs > 2) gs = 2;
        for (int ts = 0; ts < gs; ++ts) {
            const float* hr = hb[p];
            float*       hw = hb[p ^ 1];
            float4 a0[5], a1[5], a2[5], a3[5];
            #pragma unroll
            for (int j = 0; j < 5; ++j) { float4 b = bs4[j]; a0[j] = b; a1[j] = b; a2[j] = b; a3[j] = b; }
            #pragma unroll
            for (int k = 0; k < Dn; ++k) {               // x part
                float4 z = *(const float4*)&xt[ts * XTS + k * RS + bq];
                #pragma unroll
                for (int j = 0; j < 5; ++j) {
                    float4 w = wq4[k * 5 + j];
                    fma4(a0[j], z.x, w); fma4(a1[j], z.y, w);
                    fma4(a2[j], z.z, w); fma4(a3[j], z.w, w);
                }
            }
            #pragma unroll
            for (int k = 0; k < Dn; ++k) {               // h part
                float4 z = *(const float4*)&hr[k * RS + bq];
                #pragma unroll
                for (int j = 0; j < 5; ++j) {
                    float4 w = wq4[(Dn + k) * 5 + j];
                    fma4(a0[j], z.x, w); fma4(a1[j], z.y, w);
                    fma4(a2[j], z.z, w); fma4(a3[j], z.w, w);
                }
            }
            #pragma unroll
            for (int ei = 0; ei < 5; ++ei) {
                float4 hv;
                GATE4(a0, c0[ei], hv.x);
                GATE4(a1, c1[ei], hv.y);
                GATE4(a2, c2[ei], hv.z);
                GATE4(a3, c3[ei], hv.w);
                if (ei < nE) *(float4*)&hw[(e0 + ei) * RS + bq] = hv;
            }
            __syncthreads();
            p ^= 1;
        }
    }

    // ---- phase 2: free-running, out staged transposed then bulk-stored ----
    for (int tp0 = 0; tp0 < nout; tp0 += 2) {
        int gs = nout - tp0; if (gs > 2) gs = 2;
        for (int ts = 0; ts < gs; ++ts) {
            const float* hr = hb[p];
            float*       hw = hb[p ^ 1];
            float4 a0[5], a1[5], a2[5], a3[5];
            #pragma unroll
            for (int j = 0; j < 5; ++j) { float4 b = bc4[j]; a0[j] = b; a1[j] = b; a2[j] = b; a3[j] = b; }
            #pragma unroll
            for (int k = 0; k < Dn; ++k) {
                float4 z = *(const float4*)&hr[k * RS + bq];
                #pragma unroll
                for (int j = 0; j < 5; ++j) {
                    float4 w = cz4[k * 5 + j];
                    fma4(a0[j], z.x, w); fma4(a1[j], z.y, w);
                    fma4(a2[j], z.z, w); fma4(a3[j], z.w, w);
                }
            }
            #pragma unroll
            for (int ei = 0; ei < 5; ++ei) {
                float4 hv;
                GATE4(a0, c0[ei], hv.x);
                GATE4(a1, c1[ei], hv.y);
                GATE4(a2, c2[ei], hv.z);
                GATE4(a3, c3[ei], hv.w);
                if (ei < nE) *(float4*)&hw[(e0 + ei) * RS + bq] = hv;
            }
            __syncthreads();
            // head on freshly-written h_new (hw), staged into xt as out tile
            float4 o0[2] = { bl4[0], bl4[1] };
            float4 o1[2] = { bl4[0], bl4[1] };
            float4 o2[2] = { bl4[0], bl4[1] };
            float4 o3[2] = { bl4[0], bl4[1] };
            #pragma unroll
            for (int k = 0; k < Dn; ++k) {
                float4 z = *(const float4*)&hw[k * RS + bq];
                float4 w0 = wl4[k * 2 + 0], w1 = wl4[k * 2 + 1];
                fma4(o0[0], z.x, w0); fma4(o0[1], z.x, w1);
                fma4(o1[0], z.y, w0); fma4(o1[1], z.y, w1);
                fma4(o2[0], z.z, w0); fma4(o2[1], z.z, w1);
                fma4(o3[0], z.w, w0); fma4(o3[1], z.w, w1);
            }
            #pragma unroll
            for (int ei = 0; ei < 5; ++ei) {
                if (ei < nE) {
                    float4 ov;
                    ov.x = getc(o0[ei >> 2], ei & 3);
                    ov.y = getc(o1[ei >> 2], ei & 3);
                    ov.z = getc(o2[ei >> 2], ei & 3);
                    ov.w = getc(o3[ei >> 2], ei & 3);
                    *(float4*)&xt[ts * XTS + (e0 + ei) * RS + bq] = ov;
                }
            }
            p ^= 1;
        }
        __syncthreads();   // out tile complete
        #pragma unroll
        for (int i = 0; i < 34; ++i) {
            int f  = tid + 256 * i;
            int bb = f / 34, rr = f - 34 * bb;
            int ts = rr / Dn, d = rr - Dn * ts;
            if (ts < gs)
                out[(long)(b0 + bb) * (nout * Dn) + (tp0 + ts) * Dn + d] = xt[ts * XTS + d * RS + bb];
        }
        // next group's xt writes (head) occur only after its own gates barrier -> safe
    }
}

extern "C" void kernel_launch(void* const* d_in, const int* in_sizes, int n_in,
                              void* d_out, int out_size, void* d_ws, size_t ws_size,
                              hipStream_t stream) {
    (void)in_sizes; (void)n_in; (void)ws_size; (void)out_size; (void)d_ws;
    const float* x     = (const float*)d_in[0];
    const float* W_ih  = (const float*)d_in[1];
    const float* W_hh  = (const float*)d_in[2];
    const float* b_ih  = (const float*)d_in[3];
    const float* b_hh  = (const float*)d_in[4];
    const float* W_lin = (const float*)d_in[5];
    const float* b_lin = (const float*)d_in[6];
    const float* m_ih  = (const float*)d_in[7];
    const float* m_hh  = (const float*)d_in[8];
    const int*   slb   = (const int*)d_in[9];
    float* out = (float*)d_out;

    lstm_setup<<<dim3(1), dim3(256), 0, stream>>>(
        W_ih, W_hh, b_ih, b_hh, W_lin, b_lin, m_ih, m_hh);
    lstm_main<<<dim3(256), dim3(256), 0, stream>>>(x, slb, out);
}